// Round 12
// baseline (580.705 us; speedup 1.0000x reference)
//
#include <hip/hip_runtime.h>
#include <hip/hip_bf16.h>
#include <math.h>

#define CIN   64
#define COUT  32
#define K1V   17
#define HV    4
#define RPB   64          // rows per proj block
#define XPAD  68          // LDS x-row stride (floats)
#define NXCD  8

typedef float v4f __attribute__((ext_vector_type(4)));

// Kernel A (R5 structure, best measured): xp[r,o] = sum_i x[r,i]*W[o,i]+b[o]
// 64-row x tile in LDS; wave w owns outs [8w,8w+8) -> W/b wave-uniform
// (readfirstlane) -> scalar s_loads; x fragments via ds_read_b128.
__global__ __launch_bounds__(256) void proj_kernel(
    const float* __restrict__ x, const float* __restrict__ W,
    const float* __restrict__ b, float* __restrict__ xp, long nrows) {
  __shared__ float Xl[RPB * XPAD];   // 17408 B
  int tid = threadIdx.x;
  long r0 = (long)blockIdx.x * RPB;

  const v4f* xg = (const v4f*)(x + r0 * CIN);
#pragma unroll
  for (int s = 0; s < 4; ++s) {
    int fi  = tid + s * 256;
    int row = fi >> 4;
    int col = (fi & 15) << 2;
    *(v4f*)&Xl[row * XPAD + col] = xg[fi];
  }
  __syncthreads();

  int wv   = __builtin_amdgcn_readfirstlane(tid >> 6);  // wave id (SGPR)
  int lane = tid & 63;
  long r = r0 + lane;
  if (r >= nrows) return;

  const float* Wb = W + wv * 8 * CIN;   // uniform base
  float acc[8];
#pragma unroll
  for (int oo = 0; oo < 8; ++oo) acc[oo] = b[wv * 8 + oo];

#pragma unroll
  for (int j = 0; j < CIN / 4; ++j) {
    v4f xv = *(const v4f*)&Xl[lane * XPAD + j * 4];
#pragma unroll
    for (int oo = 0; oo < 8; ++oo) {
      v4f w4 = *(const v4f*)(Wb + oo * CIN + j * 4);  // s_load_dwordx4
      acc[oo] = fmaf(xv.x, w4.x,
                fmaf(xv.y, w4.y,
                fmaf(xv.z, w4.z,
                fmaf(xv.w, w4.w, acc[oo]))));
    }
  }

  float* op = xp + r * COUT + wv * 8;
  v4f lo = { acc[0], acc[1], acc[2], acc[3] };
  v4f hi = { acc[4], acc[5], acc[6], acc[7] };
  *(v4f*)op       = lo;
  *(v4f*)(op + 4) = hi;
}

// Kernel C: persistent blocks, TRUE XCD confinement. Each block reads its
// physical XCD id (HW_REG_XCC_ID, id=20, offset 0, size 32 -> imm 63508;
// HW-verified returns 0..7 on MI355X) and drains that XCD's work queue:
// queue q owns bt slices [q*btPerXcd, (q+1)*btPerXcd), group-major. So each
// 1.28MB xp slice is gathered by exactly ONE XCD's L2 (kills the 5x slice
// refetch = 149MB FETCH). After its own queue empties, a block steals from
// the other queues -> correctness never depends on the XCC read.
// Item body = exact R5 gcn: 8 nodes x 32 ch, thread owns 4 heads, 17 scalar
// coalesced gathers, nt stores.
__global__ __launch_bounds__(256) void gcn_kernel(
    const float* __restrict__ xp,    // (BT, N, 32)
    const float* __restrict__ dist,  // (N, K1)
    const int*   __restrict__ nn,    // (N, K1)
    float* __restrict__ out,         // (BT, N, H, 32)
    int*   __restrict__ ctr,         // 8 queue counters (zeroed per launch)
    int BT, int N, int ngroups, int btPerXcd, int perXcd) {
  __shared__ float wl[8][K1V][HV];
  __shared__ float dl[8][K1V];
  __shared__ int   nl[8][K1V];
  __shared__ float dagl[8][HV];
  __shared__ int   s_item;

  int tid = threadIdx.x;
  int xcc = __builtin_amdgcn_s_getreg(63508) & (NXCD - 1);  // HW_REG_XCC_ID

  for (int a = 0; a < NXCD; ++a) {
    int q = (xcc + a) & (NXCD - 1);
    for (;;) {
      __syncthreads();               // protect s_item + tables from prev item
      if (tid == 0) s_item = atomicAdd(&ctr[q], 1);
      __syncthreads();
      int item = s_item;
      if (item >= perXcd) break;     // uniform across block

      int bt = q * btPerXcd + item / ngroups;
      int n0 = (item % ngroups) * 8;
      bool ok = (bt < BT);

      if (ok && tid < 8 * K1V) {     // 136 builder threads
        int l = tid / K1V, k = tid % K1V;
        int n_ = n0 + l;
        float w0 = 0, w1 = 0, w2 = 0, w3 = 0, dc = 0;
        int idx = 0;
        if (n_ < N) {
          float d = dist[(long)n_ * K1V + k];
          idx = nn[(long)n_ * K1V + k];
          float d2 = d * d;
          w0 = __expf(-d2 * 0.25f);
          w1 = __expf(-d2 * 0.50f);
          w2 = __expf(-d2 * 0.75f);
          w3 = __expf(-d2);
          if (idx == -1) { w0 = w1 = w2 = w3 = 0.0f; }
          if (w0 < 1e-5f) w0 = 0.0f;
          if (w1 < 1e-5f) w1 = 0.0f;
          if (w2 < 1e-5f) w2 = 0.0f;
          if (w3 < 1e-5f) w3 = 0.0f;
          dc = isinf(d) ? 0.0f : d;
          if (idx < 0 || idx >= N) idx = 0;   // its w==0; safe address
        }
        wl[l][k][0] = w0; wl[l][k][1] = w1; wl[l][k][2] = w2; wl[l][k][3] = w3;
        dl[l][k] = dc; nl[l][k] = idx;
      }
      __syncthreads();

      if (ok && tid < 8 * HV) {      // fold dist_agg once per (node, head)
        int l = tid >> 2, h = tid & 3;
        float s = 0.0f;
#pragma unroll
        for (int k = 0; k < K1V; ++k) s = fmaf(wl[l][k][h], dl[l][k], s);
        dagl[l][h] = s;
      }
      __syncthreads();

      if (ok) {
        int ln = tid >> 5;           // local node
        int c  = tid & 31;           // channel
        int n  = n0 + ln;
        if (n < N) {
          const float* base = xp + (size_t)bt * N * COUT + c;
          float a0 = dagl[ln][0], a1 = dagl[ln][1];
          float a2 = dagl[ln][2], a3 = dagl[ln][3];
#pragma unroll
          for (int k = 0; k < K1V; ++k) {
            int   idx = nl[ln][k];
            float v   = base[(size_t)idx * COUT];
            v4f w4 = *(const v4f*)&wl[ln][k][0];
            a0 = fmaf(w4.x, v, a0);
            a1 = fmaf(w4.y, v, a1);
            a2 = fmaf(w4.z, v, a2);
            a3 = fmaf(w4.w, v, a3);
          }
          float* ob = out + (((size_t)bt * N + n) * HV) * COUT + c;
          __builtin_nontemporal_store(a0, ob);
          __builtin_nontemporal_store(a1, ob + COUT);
          __builtin_nontemporal_store(a2, ob + 2 * COUT);
          __builtin_nontemporal_store(a3, ob + 3 * COUT);
        }
      }
    }
  }
}

extern "C" void kernel_launch(void* const* d_in, const int* in_sizes, int n_in,
                              void* d_out, int out_size, void* d_ws, size_t ws_size,
                              hipStream_t stream) {
  const float* x    = (const float*)d_in[0];
  const float* W    = (const float*)d_in[1];
  const float* b    = (const float*)d_in[2];
  const float* dist = (const float*)d_in[3];
  const int*   nn   = (const int*)d_in[4];
  float* out = (float*)d_out;

  // ws layout: [0,256): queue counters | [256, ...): xp (30.72 MB)
  int*   ctr = (int*)d_ws;
  float* xp  = (float*)((char*)d_ws + 256);

  int  N  = in_sizes[4] / K1V;                 // 10000
  long M  = (long)in_sizes[0] / CIN;           // BT * N = 240000
  int  BT = (int)(M / N);                      // 24

  hipMemsetAsync(ctr, 0, NXCD * sizeof(int), stream);  // deterministic queues

  proj_kernel<<<(int)((M + RPB - 1) / RPB), 256, 0, stream>>>(x, W, b, xp, M);

  int ngroups   = (N + 7) / 8;                 // 1250
  int btPerXcd  = (BT + NXCD - 1) / NXCD;      // 3
  int perXcd    = ngroups * btPerXcd;          // 3750 items per XCD queue
  gcn_kernel<<<2048, 256, 0, stream>>>(xp, dist, nn, out, ctr,
                                       BT, N, ngroups, btPerXcd, perXcd);
}

// Round 13
// 76.717 us; speedup vs baseline: 7.5695x; 7.5695x over previous
//
#include <hip/hip_runtime.h>
#include <hip/hip_bf16.h>
#include <math.h>

#define CIN   64
#define COUT  32
#define K1V   17
#define HV    4
#define XSTR  72          // LDS row stride in bf16 units: 144B -> 16B-aligned b128 reads, <=4-way conflicts

typedef float v4f __attribute__((ext_vector_type(4)));
typedef unsigned int v2u __attribute__((ext_vector_type(2)));
typedef short bf8s __attribute__((ext_vector_type(8)));   // 8 bf16 = 4 VGPRs (MFMA A/B frag)
typedef float f32x16 __attribute__((ext_vector_type(16)));

__device__ __forceinline__ unsigned short f2bf(float f) { // RNE float->bf16
  unsigned u = __builtin_bit_cast(unsigned, f);
  unsigned r = 0x7FFFu + ((u >> 16) & 1u);
  return (unsigned short)((u + r) >> 16);
}
__device__ __forceinline__ unsigned pack2(float lo, float hi) {
  return (unsigned)f2bf(lo) | ((unsigned)f2bf(hi) << 16);
}

// Kernel A (MFMA): xp[r,o] = sum_i x[r,i]*W[o,i] + b[o]
// Block = 256 thr = 4 waves; each wave computes a 32-row x 32-col tile with
// 4 x mfma_f32_32x32x16_bf16 (K=64). X tile (128 rows) + W staged in LDS as
// bf16. C = X * W^T: B-frag lane (col o, k-slice) reads W[o][k..k+8) which
// is contiguous in W (the gemm_bt-friendly case).
// C/D layout (m74/m101 verified): col=lane&31, row=(reg&3)+8*(reg>>2)+4*(lane>>5).
__global__ __launch_bounds__(256) void proj_kernel(
    const float* __restrict__ x, const float* __restrict__ W,
    const float* __restrict__ b, float* __restrict__ xp, long nrows) {
  __shared__ unsigned short Xb[128 * XSTR];  // 18432 B
  __shared__ unsigned short Wb[32 * XSTR];   //  4608 B
  int tid = threadIdx.x;
  long r0 = (long)blockIdx.x * 128;
  if (r0 >= nrows) return;

  {  // stage W: 32x64 fp32 -> bf16 (512 float4)
    const v4f* wg = (const v4f*)W;
#pragma unroll
    for (int s = 0; s < 2; ++s) {
      int fi  = tid + s * 256;
      v4f wv  = wg[fi];
      int row = fi >> 4, c4 = fi & 15;
      v2u p = { pack2(wv.x, wv.y), pack2(wv.z, wv.w) };
      *(v2u*)&Wb[row * XSTR + c4 * 4] = p;
    }
  }
  {  // stage X: 128x64 fp32 -> bf16 (2048 float4, coalesced)
    const v4f* xg = (const v4f*)(x + r0 * CIN);
#pragma unroll
    for (int s = 0; s < 8; ++s) {
      int fi  = tid + s * 256;
      v4f xv  = xg[fi];
      int row = fi >> 4, c4 = fi & 15;
      v2u p = { pack2(xv.x, xv.y), pack2(xv.z, xv.w) };
      *(v2u*)&Xb[row * XSTR + c4 * 4] = p;
    }
  }
  __syncthreads();

  int wv = tid >> 6;
  int l  = tid & 63;
  int lr = l & 31;            // A row / B col within tile
  int lh = l >> 5;            // k-half (0/1): k = ks*16 + lh*8 + j

  f32x16 acc;
#pragma unroll
  for (int i = 0; i < 16; ++i) acc[i] = 0.0f;

  int arow = wv * 32 + lr;
#pragma unroll
  for (int ks = 0; ks < 4; ++ks) {
    bf8s a  = *(const bf8s*)&Xb[arow * XSTR + ks * 16 + lh * 8];  // 16B-aligned
    bf8s bb = *(const bf8s*)&Wb[lr   * XSTR + ks * 16 + lh * 8];
    acc = __builtin_amdgcn_mfma_f32_32x32x16_bf16(a, bb, acc, 0, 0, 0);
  }

  float bias = b[lr];
  float* outb = xp + (r0 + wv * 32) * COUT;
#pragma unroll
  for (int r = 0; r < 16; ++r) {
    int rr = (r & 3) + 8 * (r >> 2) + 4 * lh;
    outb[(size_t)rr * COUT + lr] = acc[r] + bias;   // half-wave = 128B row, coalesced
  }
}

// Kernel C (exact R5/86.9us structure): grid (node_groups, BT), x fastest
// -> co-resident blocks share one 1.28MB slice (L2-hot). Block = 8 nodes x
// 32 ch; thread owns all 4 heads of one (node, ch); 17 scalar coalesced
// gathers; nt stores.
__global__ __launch_bounds__(256) void gcn_kernel(
    const float* __restrict__ xp,    // (BT, N, 32)
    const float* __restrict__ dist,  // (N, K1)
    const int*   __restrict__ nn,    // (N, K1)
    float* __restrict__ out,         // (BT, N, H, 32)
    int N) {
  __shared__ float wl[8][K1V][HV];
  __shared__ float dl[8][K1V];
  __shared__ int   nl[8][K1V];
  __shared__ float dagl[8][HV];

  int tid = threadIdx.x;
  int bt  = blockIdx.y;
  int n0  = blockIdx.x * 8;

  if (tid < 8 * K1V) {        // 136 builder threads
    int l = tid / K1V, k = tid % K1V;
    int n_ = n0 + l;
    float w0 = 0, w1 = 0, w2 = 0, w3 = 0, dc = 0;
    int idx = 0;
    if (n_ < N) {
      float d = dist[(long)n_ * K1V + k];
      idx = nn[(long)n_ * K1V + k];
      float d2 = d * d;
      w0 = __expf(-d2 * 0.25f);
      w1 = __expf(-d2 * 0.50f);
      w2 = __expf(-d2 * 0.75f);
      w3 = __expf(-d2);
      if (idx == -1) { w0 = w1 = w2 = w3 = 0.0f; }
      if (w0 < 1e-5f) w0 = 0.0f;
      if (w1 < 1e-5f) w1 = 0.0f;
      if (w2 < 1e-5f) w2 = 0.0f;
      if (w3 < 1e-5f) w3 = 0.0f;
      dc = isinf(d) ? 0.0f : d;
      if (idx < 0 || idx >= N) idx = 0;   // its w==0; safe address
    }
    wl[l][k][0] = w0; wl[l][k][1] = w1; wl[l][k][2] = w2; wl[l][k][3] = w3;
    dl[l][k] = dc; nl[l][k] = idx;
  }
  __syncthreads();

  if (tid < 8 * HV) {         // fold dist_agg once per (node, head)
    int l = tid >> 2, h = tid & 3;
    float s = 0.0f;
#pragma unroll
    for (int k = 0; k < K1V; ++k) s = fmaf(wl[l][k][h], dl[l][k], s);
    dagl[l][h] = s;
  }
  __syncthreads();

  int ln = tid >> 5;          // local node
  int c  = tid & 31;          // channel
  int n  = n0 + ln;
  if (n >= N) return;

  const float* base = xp + (size_t)bt * N * COUT + c;
  float a0 = dagl[ln][0], a1 = dagl[ln][1], a2 = dagl[ln][2], a3 = dagl[ln][3];

#pragma unroll
  for (int k = 0; k < K1V; ++k) {
    int   idx = nl[ln][k];
    float v   = base[(size_t)idx * COUT];
    v4f w4 = *(const v4f*)&wl[ln][k][0];
    a0 = fmaf(w4.x, v, a0);
    a1 = fmaf(w4.y, v, a1);
    a2 = fmaf(w4.z, v, a2);
    a3 = fmaf(w4.w, v, a3);
  }

  float* ob = out + (((size_t)bt * N + n) * HV) * COUT + c;
  __builtin_nontemporal_store(a0, ob);
  __builtin_nontemporal_store(a1, ob + COUT);
  __builtin_nontemporal_store(a2, ob + 2 * COUT);
  __builtin_nontemporal_store(a3, ob + 3 * COUT);
}

extern "C" void kernel_launch(void* const* d_in, const int* in_sizes, int n_in,
                              void* d_out, int out_size, void* d_ws, size_t ws_size,
                              hipStream_t stream) {
  const float* x    = (const float*)d_in[0];
  const float* W    = (const float*)d_in[1];
  const float* b    = (const float*)d_in[2];
  const float* dist = (const float*)d_in[3];
  const int*   nn   = (const int*)d_in[4];
  float* out = (float*)d_out;
  float* xp  = (float*)d_ws;   // (BT, N, 32) fp32 = 30.72 MB

  int  N  = in_sizes[4] / K1V;                 // 10000
  long M  = (long)in_sizes[0] / CIN;           // BT * N = 240000
  int  BT = (int)(M / N);                      // 24

  proj_kernel<<<(int)((M + 127) / 128), 256, 0, stream>>>(x, W, b, xp, M);

  dim3 grid((N + 7) / 8, BT);                  // 1250 x 24, x fastest
  gcn_kernel<<<grid, 256, 0, stream>>>(xp, dist, nn, out, N);
}

// Round 14
// 70.042 us; speedup vs baseline: 8.2908x; 1.0953x over previous
//
#include <hip/hip_runtime.h>
#include <hip/hip_bf16.h>
#include <math.h>

#define CIN   64
#define COUT  32
#define K1V   17
#define HV    4

typedef float v4f __attribute__((ext_vector_type(4)));
typedef unsigned int v4u __attribute__((ext_vector_type(4)));
typedef short bf8s __attribute__((ext_vector_type(8)));   // 8 bf16 = 4 VGPRs (MFMA A/B frag)
typedef float f32x16 __attribute__((ext_vector_type(16)));
typedef unsigned short u16;

__device__ __forceinline__ u16 f2bf(float f) {            // RNE float->bf16
  unsigned u = __builtin_bit_cast(unsigned, f);
  unsigned r = 0x7FFFu + ((u >> 16) & 1u);
  return (u16)((u + r) >> 16);
}
__device__ __forceinline__ unsigned pack2(float lo, float hi) {
  return (unsigned)f2bf(lo) | ((unsigned)f2bf(hi) << 16);
}
__device__ __forceinline__ float bf2f(u16 h) {
  unsigned u = ((unsigned)h) << 16;
  return __builtin_bit_cast(float, u);
}

// Kernel A (MFMA, zero-LDS): xp16[r,o] = bf16(sum_i x[r,i]*W[o,i] + b[o])
// Wave computes 32 rows x 32 cols with 4x mfma_f32_32x32x16_bf16.
// A-frag (lane: lr=l&31, lh=l>>5): x[row=r0+lr][k=ks*16+lh*8+j] -- 8
// contiguous fp32 -> two direct v4f loads, packed to bf16 in-register.
// B-frag: W[col=lr][same k] -- same pattern, L1-hot (8KB).
// C/D (m74/m101): col=lane&31, row=(reg&3)+8*(reg>>2)+4*(lane>>5).
__global__ __launch_bounds__(256) void proj_kernel(
    const float* __restrict__ x, const float* __restrict__ W,
    const float* __restrict__ b, u16* __restrict__ xp, long nrows) {
  int tid = threadIdx.x;
  int wv  = tid >> 6;
  int l   = tid & 63;
  int lr  = l & 31;
  int lh  = l >> 5;
  long rbase = (long)blockIdx.x * 128 + wv * 32;   // M = 240000 = 1875*128, no tail
  if (rbase + lr >= nrows) return;

  const float* xr = x + (rbase + lr) * CIN;
  const float* wr = W + (long)lr * CIN;

  f32x16 acc;
#pragma unroll
  for (int i = 0; i < 16; ++i) acc[i] = 0.0f;

#pragma unroll
  for (int ks = 0; ks < 4; ++ks) {
    int k0 = ks * 16 + lh * 8;
    v4f xa = *(const v4f*)(xr + k0);
    v4f xb = *(const v4f*)(xr + k0 + 4);
    v4f wa = *(const v4f*)(wr + k0);
    v4f wb = *(const v4f*)(wr + k0 + 4);
    v4u au = { pack2(xa.x, xa.y), pack2(xa.z, xa.w),
               pack2(xb.x, xb.y), pack2(xb.z, xb.w) };
    v4u bu = { pack2(wa.x, wa.y), pack2(wa.z, wa.w),
               pack2(wb.x, wb.y), pack2(wb.z, wb.w) };
    acc = __builtin_amdgcn_mfma_f32_32x32x16_bf16(
        __builtin_bit_cast(bf8s, au), __builtin_bit_cast(bf8s, bu), acc, 0, 0, 0);
  }

  float bias = b[lr];
  u16* outb = xp + rbase * COUT;
#pragma unroll
  for (int r = 0; r < 16; ++r) {
    int rr = (r & 3) + 8 * (r >> 2) + 4 * lh;
    outb[(size_t)rr * COUT + lr] = f2bf(acc[r] + bias);  // half-wave = 64B row seg
  }
}

// Kernel C (R5-exact structure, bf16 gathers): grid (node_groups, BT), x
// fastest -> co-resident blocks share one 640KB bf16 slice (L2-hot).
// Block = 8 nodes x 32 ch; thread owns all 4 heads of one (node, ch);
// 17 scalar coalesced bf16 gathers; nt stores.
__global__ __launch_bounds__(256) void gcn_kernel(
    const u16*   __restrict__ xp,    // (BT, N, 32) bf16
    const float* __restrict__ dist,  // (N, K1)
    const int*   __restrict__ nn,    // (N, K1)
    float* __restrict__ out,         // (BT, N, H, 32)
    int N) {
  __shared__ float wl[8][K1V][HV];
  __shared__ float dl[8][K1V];
  __shared__ int   nl[8][K1V];
  __shared__ float dagl[8][HV];

  int tid = threadIdx.x;
  int bt  = blockIdx.y;
  int n0  = blockIdx.x * 8;

  if (tid < 8 * K1V) {        // 136 builder threads
    int l = tid / K1V, k = tid % K1V;
    int n_ = n0 + l;
    float w0 = 0, w1 = 0, w2 = 0, w3 = 0, dc = 0;
    int idx = 0;
    if (n_ < N) {
      float d = dist[(long)n_ * K1V + k];
      idx = nn[(long)n_ * K1V + k];
      float d2 = d * d;
      w0 = __expf(-d2 * 0.25f);
      w1 = __expf(-d2 * 0.50f);
      w2 = __expf(-d2 * 0.75f);
      w3 = __expf(-d2);
      if (idx == -1) { w0 = w1 = w2 = w3 = 0.0f; }
      if (w0 < 1e-5f) w0 = 0.0f;
      if (w1 < 1e-5f) w1 = 0.0f;
      if (w2 < 1e-5f) w2 = 0.0f;
      if (w3 < 1e-5f) w3 = 0.0f;
      dc = isinf(d) ? 0.0f : d;
      if (idx < 0 || idx >= N) idx = 0;   // its w==0; safe address
    }
    wl[l][k][0] = w0; wl[l][k][1] = w1; wl[l][k][2] = w2; wl[l][k][3] = w3;
    dl[l][k] = dc; nl[l][k] = idx;
  }
  __syncthreads();

  if (tid < 8 * HV) {         // fold dist_agg once per (node, head)
    int l = tid >> 2, h = tid & 3;
    float s = 0.0f;
#pragma unroll
    for (int k = 0; k < K1V; ++k) s = fmaf(wl[l][k][h], dl[l][k], s);
    dagl[l][h] = s;
  }
  __syncthreads();

  int ln = tid >> 5;          // local node
  int c  = tid & 31;          // channel
  int n  = n0 + ln;
  if (n >= N) return;

  const u16* base = xp + (size_t)bt * N * COUT + c;
  float a0 = dagl[ln][0], a1 = dagl[ln][1], a2 = dagl[ln][2], a3 = dagl[ln][3];

#pragma unroll
  for (int k = 0; k < K1V; ++k) {
    int   idx = nl[ln][k];
    float v   = bf2f(base[(size_t)idx * COUT]);
    v4f w4 = *(const v4f*)&wl[ln][k][0];
    a0 = fmaf(w4.x, v, a0);
    a1 = fmaf(w4.y, v, a1);
    a2 = fmaf(w4.z, v, a2);
    a3 = fmaf(w4.w, v, a3);
  }

  float* ob = out + (((size_t)bt * N + n) * HV) * COUT + c;
  __builtin_nontemporal_store(a0, ob);
  __builtin_nontemporal_store(a1, ob + COUT);
  __builtin_nontemporal_store(a2, ob + 2 * COUT);
  __builtin_nontemporal_store(a3, ob + 3 * COUT);
}

extern "C" void kernel_launch(void* const* d_in, const int* in_sizes, int n_in,
                              void* d_out, int out_size, void* d_ws, size_t ws_size,
                              hipStream_t stream) {
  const float* x    = (const float*)d_in[0];
  const float* W    = (const float*)d_in[1];
  const float* b    = (const float*)d_in[2];
  const float* dist = (const float*)d_in[3];
  const int*   nn   = (const int*)d_in[4];
  float* out = (float*)d_out;
  u16*   xp  = (u16*)d_ws;     // (BT, N, 32) bf16 = 15.36 MB

  int  N  = in_sizes[4] / K1V;                 // 10000
  long M  = (long)in_sizes[0] / CIN;           // BT * N = 240000
  int  BT = (int)(M / N);                      // 24

  proj_kernel<<<(int)((M + 127) / 128), 256, 0, stream>>>(x, W, b, xp, M);

  dim3 grid((N + 7) / 8, BT);                  // 1250 x 24, x fastest
  gcn_kernel<<<grid, 256, 0, stream>>>(xp, dist, nn, out, N);
}

// Round 15
// 62.072 us; speedup vs baseline: 9.3554x; 1.1284x over previous
//
#include <hip/hip_runtime.h>
#include <hip/hip_bf16.h>
#include <math.h>

#define CIN   64
#define COUT  32
#define K1V   17
#define HV    4
#define BTILE 3           // bt slices per gcn block (24 = 8 tiles x 3)

typedef float v4f __attribute__((ext_vector_type(4)));
typedef unsigned int v4u __attribute__((ext_vector_type(4)));
typedef short bf8s __attribute__((ext_vector_type(8)));   // 8 bf16 = 4 VGPRs (MFMA A/B frag)
typedef float f32x16 __attribute__((ext_vector_type(16)));
typedef unsigned short u16;

__device__ __forceinline__ u16 f2bf(float f) {            // RNE float->bf16
  unsigned u = __builtin_bit_cast(unsigned, f);
  unsigned r = 0x7FFFu + ((u >> 16) & 1u);
  return (u16)((u + r) >> 16);
}
__device__ __forceinline__ unsigned pack2(float lo, float hi) {
  return (unsigned)f2bf(lo) | ((unsigned)f2bf(hi) << 16);
}
__device__ __forceinline__ float bf2f(u16 h) {
  unsigned u = ((unsigned)h) << 16;
  return __builtin_bit_cast(float, u);
}

// Kernel A (MFMA, zero-LDS — R14 best): xp16[r,o] = bf16(x[r,:]*W[o,:]+b[o])
// Wave computes 32 rows x 32 cols with 4x mfma_f32_32x32x16_bf16.
// A-frag: x[row=rbase+lr][k=ks*16+lh*8+j] = 8 contiguous fp32 -> 2 v4f loads,
// packed to bf16 in-register. B-frag: W[col=lr][same k], L1-hot.
// C/D (m74/m101): col=lane&31, row=(reg&3)+8*(reg>>2)+4*(lane>>5).
__global__ __launch_bounds__(256) void proj_kernel(
    const float* __restrict__ x, const float* __restrict__ W,
    const float* __restrict__ b, u16* __restrict__ xp, long nrows) {
  int tid = threadIdx.x;
  int wv  = tid >> 6;
  int l   = tid & 63;
  int lr  = l & 31;
  int lh  = l >> 5;
  long rbase = (long)blockIdx.x * 128 + wv * 32;   // M = 240000 = 1875*128
  if (rbase + lr >= nrows) return;

  const float* xr = x + (rbase + lr) * CIN;
  const float* wr = W + (long)lr * CIN;

  f32x16 acc;
#pragma unroll
  for (int i = 0; i < 16; ++i) acc[i] = 0.0f;

#pragma unroll
  for (int ks = 0; ks < 4; ++ks) {
    int k0 = ks * 16 + lh * 8;
    v4f xa = *(const v4f*)(xr + k0);
    v4f xb = *(const v4f*)(xr + k0 + 4);
    v4f wa = *(const v4f*)(wr + k0);
    v4f wb = *(const v4f*)(wr + k0 + 4);
    v4u au = { pack2(xa.x, xa.y), pack2(xa.z, xa.w),
               pack2(xb.x, xb.y), pack2(xb.z, xb.w) };
    v4u bu = { pack2(wa.x, wa.y), pack2(wa.z, wa.w),
               pack2(wb.x, wb.y), pack2(wb.z, wb.w) };
    acc = __builtin_amdgcn_mfma_f32_32x32x16_bf16(
        __builtin_bit_cast(bf8s, au), __builtin_bit_cast(bf8s, bu), acc, 0, 0, 0);
  }

  float bias = b[lr];
  u16* outb = xp + rbase * COUT;
#pragma unroll
  for (int r = 0; r < 16; ++r) {
    int rr = (r & 3) + 8 * (r >> 2) + 4 * lh;
    outb[(size_t)rr * COUT + lr] = f2bf(acc[r] + bias);
  }
}

// Kernel C (R5 structure + BTILE=3): grid (node_groups, BT/3), x fastest ->
// co-resident blocks share a 1.92MB 3-slice window (fits XCD L2). Table
// built ONCE per block (amortized 3x), then per k: 3 independent gathers
// (one per slice) feed 12 FMAs -> 3x memory-level parallelism; 12 nt stores.
__global__ __launch_bounds__(256) void gcn_kernel(
    const u16*   __restrict__ xp,    // (BT, N, 32) bf16
    const float* __restrict__ dist,  // (N, K1)
    const int*   __restrict__ nn,    // (N, K1)
    float* __restrict__ out,         // (BT, N, H, 32)
    int N) {
  __shared__ float wl[8][K1V][HV];
  __shared__ float dl[8][K1V];
  __shared__ int   nl[8][K1V];
  __shared__ float dagl[8][HV];

  int tid = threadIdx.x;
  int bt0 = blockIdx.y * BTILE;
  int n0  = blockIdx.x * 8;

  if (tid < 8 * K1V) {        // 136 builder threads
    int l = tid / K1V, k = tid % K1V;
    int n_ = n0 + l;
    float w0 = 0, w1 = 0, w2 = 0, w3 = 0, dc = 0;
    int idx = 0;
    if (n_ < N) {
      float d = dist[(long)n_ * K1V + k];
      idx = nn[(long)n_ * K1V + k];
      float d2 = d * d;
      w0 = __expf(-d2 * 0.25f);
      w1 = __expf(-d2 * 0.50f);
      w2 = __expf(-d2 * 0.75f);
      w3 = __expf(-d2);
      if (idx == -1) { w0 = w1 = w2 = w3 = 0.0f; }
      if (w0 < 1e-5f) w0 = 0.0f;
      if (w1 < 1e-5f) w1 = 0.0f;
      if (w2 < 1e-5f) w2 = 0.0f;
      if (w3 < 1e-5f) w3 = 0.0f;
      dc = isinf(d) ? 0.0f : d;
      if (idx < 0 || idx >= N) idx = 0;   // its w==0; safe address
    }
    wl[l][k][0] = w0; wl[l][k][1] = w1; wl[l][k][2] = w2; wl[l][k][3] = w3;
    dl[l][k] = dc; nl[l][k] = idx;
  }
  __syncthreads();

  if (tid < 8 * HV) {         // fold dist_agg once per (node, head)
    int l = tid >> 2, h = tid & 3;
    float s = 0.0f;
#pragma unroll
    for (int k = 0; k < K1V; ++k) s = fmaf(wl[l][k][h], dl[l][k], s);
    dagl[l][h] = s;
  }
  __syncthreads();

  int ln = tid >> 5;          // local node
  int c  = tid & 31;          // channel
  int n  = n0 + ln;
  if (n >= N) return;

  int off[K1V];               // element offsets within a slice
#pragma unroll
  for (int k = 0; k < K1V; ++k) off[k] = nl[ln][k] * COUT;

  const int SL = N * COUT;    // 320000 elements per slice (fits int)
  const u16* base = xp + (size_t)bt0 * SL + c;

  float a[BTILE][HV];
#pragma unroll
  for (int t = 0; t < BTILE; ++t) {
    a[t][0] = dagl[ln][0]; a[t][1] = dagl[ln][1];
    a[t][2] = dagl[ln][2]; a[t][3] = dagl[ln][3];
  }

#pragma unroll
  for (int k = 0; k < K1V; ++k) {
    float v0 = bf2f(base[off[k]]);
    float v1 = bf2f(base[off[k] + SL]);
    float v2 = bf2f(base[off[k] + 2 * SL]);
    v4f w4 = *(const v4f*)&wl[ln][k][0];
    a[0][0] = fmaf(w4.x, v0, a[0][0]);
    a[0][1] = fmaf(w4.y, v0, a[0][1]);
    a[0][2] = fmaf(w4.z, v0, a[0][2]);
    a[0][3] = fmaf(w4.w, v0, a[0][3]);
    a[1][0] = fmaf(w4.x, v1, a[1][0]);
    a[1][1] = fmaf(w4.y, v1, a[1][1]);
    a[1][2] = fmaf(w4.z, v1, a[1][2]);
    a[1][3] = fmaf(w4.w, v1, a[1][3]);
    a[2][0] = fmaf(w4.x, v2, a[2][0]);
    a[2][1] = fmaf(w4.y, v2, a[2][1]);
    a[2][2] = fmaf(w4.z, v2, a[2][2]);
    a[2][3] = fmaf(w4.w, v2, a[2][3]);
  }

#pragma unroll
  for (int t = 0; t < BTILE; ++t) {
    float* ob = out + (((size_t)(bt0 + t) * N + n) * HV) * COUT + c;
    __builtin_nontemporal_store(a[t][0], ob);
    __builtin_nontemporal_store(a[t][1], ob + COUT);
    __builtin_nontemporal_store(a[t][2], ob + 2 * COUT);
    __builtin_nontemporal_store(a[t][3], ob + 3 * COUT);
  }
}

extern "C" void kernel_launch(void* const* d_in, const int* in_sizes, int n_in,
                              void* d_out, int out_size, void* d_ws, size_t ws_size,
                              hipStream_t stream) {
  const float* x    = (const float*)d_in[0];
  const float* W    = (const float*)d_in[1];
  const float* b    = (const float*)d_in[2];
  const float* dist = (const float*)d_in[3];
  const int*   nn   = (const int*)d_in[4];
  float* out = (float*)d_out;
  u16*   xp  = (u16*)d_ws;     // (BT, N, 32) bf16 = 15.36 MB

  int  N  = in_sizes[4] / K1V;                 // 10000
  long M  = (long)in_sizes[0] / CIN;           // BT * N = 240000
  int  BT = (int)(M / N);                      // 24

  proj_kernel<<<(int)((M + 127) / 128), 256, 0, stream>>>(x, W, b, xp, M);

  dim3 grid((N + 7) / 8, BT / BTILE);          // 1250 x 8, x fastest
  gcn_kernel<<<grid, 256, 0, stream>>>(xp, dist, nn, out, N);
}